// Round 10
// baseline (276.353 us; speedup 1.0000x reference)
//
#include <hip/hip_runtime.h>
#include <hip/hip_bf16.h>

#define HIDDEN 1024
#define NHEADS 16
#define DKH   64
#define BATCH 2
#define SEQ   2048
#define MTOT  (BATCH*SEQ)   // 4096

using bf16x8 = __attribute__((ext_vector_type(8))) short;
using f32x4  = __attribute__((ext_vector_type(4))) float;
using u16x4  = __attribute__((ext_vector_type(4))) unsigned short;

__device__ __forceinline__ unsigned short f2bf(float f) {
    union { __hip_bfloat16 h; unsigned short u; } v;
    v.h = __float2bfloat16(f);
    return v.u;
}

__device__ __forceinline__ float asfloat(unsigned int u) {
    union { unsigned int u; float f; } v; v.u = u; return v.f;
}

__device__ __forceinline__ float fexp2(float x) {
#if __has_builtin(__builtin_amdgcn_exp2f)
    return __builtin_amdgcn_exp2f(x);
#else
    return exp2f(x);
#endif
}

// async global->LDS, 16B per lane. LDS ptr must be wave-uniform (HW adds lane*16).
__device__ __forceinline__ void gload16(const unsigned short* g, unsigned short* l) {
    __builtin_amdgcn_global_load_lds((const __attribute__((address_space(1))) void*)g,
                                     (__attribute__((address_space(3))) void*)l, 16, 0, 0);
}

#define L2E 1.44269504088896340736f

// ---------------- fused prep ----------------
// bid [0,1024): bias+mask -> biasf bf16 fragment-tiled (largest read, first)
// bid [1024,2048): W -> Wt bf16 transpose
// biasf bf16: [b][qg128][t64][lane64*8], lane ln holds q = qg*16 + (ln&15),
// kv = t*32 + (ln>>4)*8 + i, value (bias+mask)*log2e.
// (round-6 lesson: f32 biasf doubled the bias demand stream; bf16 stays.)
__global__ __launch_bounds__(256) void prep(const float* __restrict__ Wq,
                                            const float* __restrict__ Wk,
                                            const float* __restrict__ Wv,
                                            const float* __restrict__ Wo,
                                            unsigned short* __restrict__ wt,
                                            const float* __restrict__ bias,
                                            const float* __restrict__ mask,
                                            unsigned short* __restrict__ biasf) {
    // overlay: W-branch float[64][65] (16640B); bias-branch ushort[16][520] (16640B)
    __shared__ __align__(16) char sh[16640];
    float (*tile)[65] = (float (*)[65])sh;
    unsigned short (*lb)[520] = (unsigned short (*)[520])sh;
    const int bid = blockIdx.x, t = threadIdx.x;
    if (bid >= 1024) {
        int r = bid - 1024;
        const int z = r >> 8; r &= 255;
        const int kb = (r >> 4) * 64, nb = (r & 15) * 64;
        const float* W = (z == 0) ? Wq : (z == 1) ? Wk : (z == 2) ? Wv : Wo;
        unsigned short* out = wt + (size_t)z * HIDDEN * HIDDEN;
        #pragma unroll
        for (int i = 0; i < 16; i++) {
            int idx = i * 256 + t; int rr = idx >> 6, c = idx & 63;
            tile[rr][c] = W[(size_t)(kb + rr) * HIDDEN + nb + c];
        }
        __syncthreads();
        #pragma unroll
        for (int i = 0; i < 16; i++) {
            int idx = i * 256 + t; int n = idx >> 6, kk = idx & 63;
            out[(size_t)(nb + n) * HIDDEN + kb + kk] = f2bf(tile[kk][n]);
        }
    } else {
        const int cb = bid;                // 0..1023
        const int chunk = cb & 3, g = (cb >> 2) & 127, b = cb >> 9;
        const float* bp = bias + ((size_t)b * SEQ + g * 16) * SEQ + chunk * 512;
        const float* mp = mask + ((size_t)b * SEQ + g * 16) * SEQ + chunk * 512;
        // load 16 rows x 512 cols, coalesced along kv
        #pragma unroll
        for (int i = 0; i < 8; i++) {
            int idx = i * 256 + t;
            int row = idx >> 7, c4 = (idx & 127) * 4;
            float4 bv4 = *(const float4*)(bp + (size_t)row * SEQ + c4);
            float4 mv4 = *(const float4*)(mp + (size_t)row * SEQ + c4);
            union { u16x4 v; unsigned short s[4]; } o;
            o.s[0] = f2bf((bv4.x + mv4.x) * L2E);
            o.s[1] = f2bf((bv4.y + mv4.y) * L2E);
            o.s[2] = f2bf((bv4.z + mv4.z) * L2E);
            o.s[3] = f2bf((bv4.w + mv4.w) * L2E);
            *(u16x4*)&lb[row][c4] = o.v;
        }
        __syncthreads();
        // emit fragment tiles: tt = chunk*16 + ttl
        const int w = t >> 6, ln = t & 63;
        const int quad = ln >> 4, c16 = ln & 15;
        unsigned short* ob = biasf + (((size_t)b * 128 + g) * 64 + chunk * 16) * 512 + ln * 8;
        #pragma unroll
        for (int it = 0; it < 4; it++) {
            int ttl = it * 4 + w;
            *(bf16x8*)(ob + (size_t)ttl * 512) = *(const bf16x8*)&lb[c16][ttl * 32 + quad * 8];
        }
    }
}

// ---------------- projections: 128x128, pipelined AF32 (PROVEN r7 config, 52.5us) ----
// r8 (64x128) and r9 (dbuf B) both regressed: at 3-4 blocks/CU the implicit
// cross-block wave overlap already covers the drain (m114/m99 lesson); LDS growth
// or tile shrink just loses occupancy. This is the verified-best structure:
// A-operand f32, loads for kk+64 issued right after the staging barrier of kk.
// LDS: A elem (r, slot s) holds X[r][s^(r&7)] bf16; B same swizzle at offset 8192.
// q -> qh [bh][q][64] (scaled 0.125*log2e)
// k -> khs [bh][t64][ks2][kvs2][lane64*8]: lane ln holds
//          K[kv = t*32 + (c16>>2)*8 + kvs*4 + (c16&3)][d = ks*32 + quad*8 + i]
// v -> vts [bh][t64][dt4][lane64*8]: lane ln holds V[kv = t*32 + quad*8 + i][d = dt*16 + c16]
__global__ __launch_bounds__(256, 2) void proj_gemm(const float* __restrict__ qf32,
                                                    const float* __restrict__ kf32,
                                                    const float* __restrict__ vf32,
                                                    const unsigned short* __restrict__ Wtall,
                                                    const float* __restrict__ bq,
                                                    const float* __restrict__ bk,
                                                    const float* __restrict__ bv,
                                                    unsigned short* __restrict__ qh,
                                                    unsigned short* __restrict__ khs,
                                                    unsigned short* __restrict__ vts) {
    __shared__ __align__(16) unsigned short smem[18432];
    const int z = blockIdx.z;
    const float* X  = (z == 0) ? qf32 : (z == 1) ? kf32 : vf32;
    const unsigned short* Wt = Wtall + (size_t)z * HIDDEN * HIDDEN;
    const float* bias = (z == 0) ? bq : (z == 1) ? bk : bv;
    const int mbase = blockIdx.x * 128, nbase = blockIdx.y * 128;
    const int tid = threadIdx.x, w = tid >> 6, ln = tid & 63;
    const int qr = (w >> 1) * 64, qc = (w & 1) * 64;
    const int g = ln >> 4, c16 = ln & 15;

    f32x4 acc[4][4];
    #pragma unroll
    for (int rt = 0; rt < 4; rt++)
        #pragma unroll
        for (int ct = 0; ct < 4; ct++) acc[rt][ct] = (f32x4){0.f, 0.f, 0.f, 0.f};

    float4 fa[4][2];
    // prologue: preload k-step 0
    #pragma unroll
    for (int pass = 0; pass < 4; pass++) {
        int L = pass * 256 + tid;
        int r = L >> 3, cc = L & 7;
        const float* p = X + (size_t)(mbase + r) * HIDDEN + cc * 8;
        fa[pass][0] = *(const float4*)p;
        fa[pass][1] = *(const float4*)(p + 4);
    }

    for (int kk = 0; kk < HIDDEN; kk += 64) {
        __syncthreads();
        // B via async DMA first (flies during the A convert)
        #pragma unroll
        for (int pass = 0; pass < 4; pass++) {
            int L = pass * 256 + tid;
            int r = L >> 3, c = (L & 7) ^ (r & 7);
            gload16(Wt + (size_t)(nbase + r) * HIDDEN + kk + c * 8,
                    smem + 8192 + (size_t)(pass * 256 + w * 64) * 8);
        }
        // A: convert prefetched regs, swizzled ds_write
        #pragma unroll
        for (int pass = 0; pass < 4; pass++) {
            int L = pass * 256 + tid;
            int r = L >> 3, cc = L & 7;
            int cs = cc ^ (r & 7);
            union { bf16x8 v; unsigned short s[8]; } o;
            o.s[0] = f2bf(fa[pass][0].x); o.s[1] = f2bf(fa[pass][0].y);
            o.s[2] = f2bf(fa[pass][0].z); o.s[3] = f2bf(fa[pass][0].w);
            o.s[4] = f2bf(fa[pass][1].x); o.s[5] = f2bf(fa[pass][1].y);
            o.s[6] = f2bf(fa[pass][1].z); o.s[7] = f2bf(fa[pass][1].w);
            *(bf16x8*)(smem + (size_t)(r * 8 + cs) * 8) = o.v;
        }
        __syncthreads();
        // issue next k-step's A loads NOW; they complete during the MFMA phase
        if (kk + 64 < HIDDEN) {
            #pragma unroll
            for (int pass = 0; pass < 4; pass++) {
                int L = pass * 256 + tid;
                int r = L >> 3, cc = L & 7;
                const float* p = X + (size_t)(mbase + r) * HIDDEN + (kk + 64) + cc * 8;
                fa[pass][0] = *(const float4*)p;
                fa[pass][1] = *(const float4*)(p + 4);
            }
        }
        #pragma unroll
        for (int ks = 0; ks < 2; ks++) {
            bf16x8 af[4], bfr[4];
            #pragma unroll
            for (int rt = 0; rt < 4; rt++) {
                int r = qr + rt * 16 + c16;
                int ch = (g + ks * 4) ^ (r & 7);
                af[rt] = *(const bf16x8*)(smem + (size_t)(r * 8 + ch) * 8);
            }
            #pragma unroll
            for (int ct = 0; ct < 4; ct++) {
                int n = qc + ct * 16 + c16;
                int ch = (g + ks * 4) ^ (n & 7);
                bfr[ct] = *(const bf16x8*)(smem + 8192 + (size_t)(n * 8 + ch) * 8);
            }
            #pragma unroll
            for (int rt = 0; rt < 4; rt++)
                #pragma unroll
                for (int ct = 0; ct < 4; ct++)
                    acc[rt][ct] = __builtin_amdgcn_mfma_f32_16x16x32_bf16(af[rt], bfr[ct], acc[rt][ct], 0, 0, 0);
        }
    }
    __syncthreads();

    const float scale = (z == 0) ? (0.125f * L2E) : 1.0f;
    float bias_v[4];
    #pragma unroll
    for (int ct = 0; ct < 4; ct++) bias_v[ct] = bias[nbase + qc + ct * 16 + c16];

    unsigned short* eld = smem + w * 4608;   // 64x72 per wave
    #pragma unroll
    for (int rt = 0; rt < 4; rt++)
        #pragma unroll
        for (int ct = 0; ct < 4; ct++)
            #pragma unroll
            for (int r4 = 0; r4 < 4; r4++) {
                int row_l = rt * 16 + g * 4 + r4;    // pos (local)
                int col_l = ct * 16 + c16;           // n (local)
                float val = (acc[rt][ct][r4] + bias_v[ct]) * scale;
                if (z == 2) eld[col_l * 72 + row_l] = f2bf(val);  // [d][pos]
                else        eld[row_l * 72 + col_l] = f2bf(val);  // [pos][d]
            }
    __syncthreads();

    const int b = mbase >> 11;
    const int pos0 = (mbase & 2047) + qr;   // multiple of 64
    const int h = (nbase + qc) >> 6;
    const int bh = b * NHEADS + h;
    if (z == 0) {
        const int row8 = ln >> 3, col8 = (ln & 7) * 8;
        unsigned short* dst0 = qh + ((size_t)bh * SEQ + pos0) * DKH;
        #pragma unroll
        for (int j = 0; j < 8; j++) {
            int row = j * 8 + row8;
            *(bf16x8*)(dst0 + row * 64 + col8) = *(const bf16x8*)&eld[row * 72 + col8];
        }
    } else if (z == 1) {
        unsigned short* base = khs + ((size_t)bh * 64 + (pos0 >> 5)) * 2048;
        const int kvp = (c16 >> 2) * 8 + (c16 & 3);
        #pragma unroll
        for (int j = 0; j < 8; j++) {
            int tloc = j >> 2, ks = (j >> 1) & 1, kvs = j & 1;
            int kvl = tloc * 32 + kvp + kvs * 4;
            *(bf16x8*)(base + tloc * 2048 + ks * 1024 + kvs * 512 + ln * 8)
                = *(const bf16x8*)&eld[kvl * 72 + ks * 32 + g * 8];
        }
    } else {
        unsigned short* base = vts + ((size_t)bh * 64 + (pos0 >> 5)) * 2048;
        #pragma unroll
        for (int j = 0; j < 8; j++) {
            int tloc = j >> 2, dt = j & 3;
            *(bf16x8*)(base + tloc * 2048 + dt * 512 + ln * 8)
                = *(const bf16x8*)&eld[(dt * 16 + c16) * 72 + tloc * 32 + g * 8];
        }
    }
}

// ---------------- attention: 2-head blocks, 512 threads ----------------
// Block = 2 heads x 64 q x 2048 kv; waves 0-3 -> head 2p, waves 4-7 -> head 2p+1,
// SAME 64 q rows. Theory: attn was bias-stream-bound (256KB bf16 bias panel per
// block, unshared between co-resident blocks -> 256MB L3 demand). Wave w and w+4
// load identical bias addresses at the same loop point -> L1 dedup -> bias L2/L3
// demand halved to 128MB. K/V staging per head-half byte-identical to the 4-wave
// version. LDS 64KB -> 2 blocks/CU = 16 waves/CU (occupancy preserved).
// Per-(head,q-row) arithmetic order unchanged -> bit-identical output.
__global__ __launch_bounds__(512, 4) void attn(const unsigned short* __restrict__ qh,
                                               const unsigned short* __restrict__ khs,
                                               const unsigned short* __restrict__ vts,
                                               const unsigned short* __restrict__ biasf,
                                               unsigned short* __restrict__ ctx) {
    __shared__ __align__(16) unsigned short smem[32768];   // half h: [h*16384 +] K 8192 | V 8192
    const int tid = threadIdx.x, w = tid >> 6, ln = tid & 63;
    const int w4 = w & 3, hh = w >> 2;       // wave-quad within head-half, head-half
    const int quad = ln >> 4, c16 = ln & 15;
    // XCD swizzle: 2 head-pairs (=4 heads) per XCD, all 32 q-blocks of a pair on
    // one XCD (K/V L2 reuse, 2MB per XCD)
    const int bid = blockIdx.x;
    const int xcd = bid & 7, jj = bid >> 3;    // jj 0..63
    const int hp = xcd * 2 + (jj >> 5);        // head-pair 0..15
    const int qb = jj & 31;                    // 64-row q block
    const int b = hp >> 3, h = (hp & 7) * 2 + hh;
    const int bh = b * NHEADS + h;

    unsigned short* mysmem = smem + hh * 16384;

    // Q B-fragments (persistent); wave owns 16 q rows of its head
    bf16x8 qf[2];
    {
        const unsigned short* qp = qh + ((size_t)bh * SEQ + qb * 64 + w4 * 16 + c16) * DKH + quad * 8;
        qf[0] = *(const bf16x8*)qp;
        qf[1] = *(const bf16x8*)(qp + 32);
    }

    const unsigned short* kT = khs + (size_t)bh * 131072;
    const unsigned short* vT = vts + (size_t)bh * 131072;
    // bias group g = qb*4 + w4 -- identical for wave w and w+4 (L1 dedup)
    const unsigned short* bb = biasf + (((size_t)(b * 128 + qb * 4 + w4) * 64) * 512) + ln * 8;

    // ones A-fragment for the denominator MFMA
    const short one_bf = (short)0x3F80;
    bf16x8 vones = {one_bf, one_bf, one_bf, one_bf, one_bf, one_bf, one_bf, one_bf};

    f32x4 accv[4];
    #pragma unroll
    for (int dt = 0; dt < 4; dt++) accv[dt] = (f32x4){0.f, 0.f, 0.f, 0.f};
    f32x4 dsum = (f32x4){0.f, 0.f, 0.f, 0.f};

    bf16x8 bA[4], bB[4];
    #pragma unroll
    for (int j = 0; j < 4; j++) bA[j] = *(const bf16x8*)(bb + j * 512);   // tile 0

    // one half-tile: stage K/V for T (own head-half), prefetch bias for T+1 into bn
    // (1-tile slack: drained by T+1's barrier), compute tile T consuming bc.
    #define HALF_TILE(T, bc, bn)                                                        \
    {                                                                                   \
        __syncthreads();   /* previous tile's ds_reads done */                          \
        {                                                                               \
            const unsigned short* ksrc = kT + (T) * 8192 + w4 * 512 + ln * 8;           \
            const unsigned short* vsrc = vT + (T) * 8192 + w4 * 512 + ln * 8;           \
            unsigned short* lk = mysmem + w4 * 512;                                     \
            unsigned short* lv = mysmem + 8192 + w4 * 512;                              \
            _Pragma("unroll")                                                           \
            for (int p = 0; p < 4; p++) {                                               \
                gload16(ksrc + p * 2048, lk + p * 2048);                                \
                gload16(vsrc + p * 2048, lv + p * 2048);                                \
            }                                                                           \
        }                                                                               \
        {                                                                               \
            const int Tn = ((T) < 15) ? (T) + 1 : 15;                                   \
            _Pragma("unroll")                                                           \
            for (int j = 0; j < 4; j++)                                                 \
                bn[j] = *(const bf16x8*)(bb + (size_t)(Tn * 4 + j) * 512);              \
        }                                                                               \
        __syncthreads();   /* drain global_load_lds */                                  \
        _Pragma("unroll")                                                               \
        for (int j = 0; j < 4; j++) {                                                   \
            bf16x8 kf00 = *(const bf16x8*)(mysmem + j * 2048 + ln * 8);                 \
            bf16x8 kf01 = *(const bf16x8*)(mysmem + j * 2048 + 512 + ln * 8);           \
            bf16x8 kf10 = *(const bf16x8*)(mysmem + j * 2048 + 1024 + ln * 8);          \
            bf16x8 kf11 = *(const bf16x8*)(mysmem + j * 2048 + 1536 + ln * 8);          \
            bf16x8 vf[4];                                                               \
            _Pragma("unroll")                                                           \
            for (int dt = 0; dt < 4; dt++)                                              \
                vf[dt] = *(const bf16x8*)(mysmem + 8192 + j * 2048 + dt * 512 + ln * 8);\
            const unsigned int* bd = (const unsigned int*)&bc[j];                       \
            f32x4 s0, s1;                                                               \
            s0[0] = asfloat(bd[0] << 16); s0[1] = asfloat(bd[0] & 0xFFFF0000u);         \
            s0[2] = asfloat(bd[1] << 16); s0[3] = asfloat(bd[1] & 0xFFFF0000u);         \
            s1[0] = asfloat(bd[2] << 16); s1[1] = asfloat(bd[2] & 0xFFFF0000u);         \
            s1[2] = asfloat(bd[3] << 16); s1[3] = asfloat(bd[3] & 0xFFFF0000u);         \
            s0 = __builtin_amdgcn_mfma_f32_16x16x32_bf16(kf00, qf[0], s0, 0, 0, 0);     \
            s0 = __builtin_amdgcn_mfma_f32_16x16x32_bf16(kf10, qf[1], s0, 0, 0, 0);     \
            s1 = __builtin_amdgcn_mfma_f32_16x16x32_bf16(kf01, qf[0], s1, 0, 0, 0);     \
            s1 = __builtin_amdgcn_mfma_f32_16x16x32_bf16(kf11, qf[1], s1, 0, 0, 0);     \
            _Pragma("unroll")                                                           \
            for (int r = 0; r < 4; r++) { s0[r] = fexp2(s0[r]); s1[r] = fexp2(s1[r]); } \
            union { bf16x8 v; __hip_bfloat162 hh2[4]; } pu;                             \
            pu.hh2[0] = __float22bfloat162_rn(make_float2(s0[0], s0[1]));               \
            pu.hh2[1] = __float22bfloat162_rn(make_float2(s0[2], s0[3]));               \
            pu.hh2[2] = __float22bfloat162_rn(make_float2(s1[0], s1[1]));               \
            pu.hh2[3] = __float22bfloat162_rn(make_float2(s1[2], s1[3]));               \
            dsum = __builtin_amdgcn_mfma_f32_16x16x32_bf16(vones, pu.v, dsum, 0, 0, 0); \
            _Pragma("unroll")                                                           \
            for (int dt = 0; dt < 4; dt++)                                              \
                accv[dt] = __builtin_amdgcn_mfma_f32_16x16x32_bf16(vf[dt], pu.v,        \
                                                                   accv[dt], 0, 0, 0); \
        }                                                                               \
    }

    for (int T = 0; T < 16; T += 2) {
        HALF_TILE(T,     bA, bB)
        HALF_TILE(T + 1, bB, bA)
    }
    #undef HALF_TILE

    // epilogue: normalize (dsum rows all equal; lane's col c16 = its q row),
    // per-wave LDS transpose (reuse smem), coalesced store
    const float inv = 1.0f / dsum[0];
    __syncthreads();   // all waves done reading staged K/V
    unsigned short* ot = smem + w * 1152;   // 16 x 72 per wave (8 waves = 9216 elems)
    #pragma unroll
    for (int dt = 0; dt < 4; dt++)
        #pragma unroll
        for (int r = 0; r < 4; r += 2) {
            union { __hip_bfloat162 hhp; unsigned int u; } pk;
            pk.hhp = __float22bfloat162_rn(make_float2(accv[dt][r] * inv,
                                                      accv[dt][r + 1] * inv));
            *(unsigned int*)&ot[c16 * 72 + dt * 16 + quad * 4 + r] = pk.u;
        }
    // wave-local write->read: in-order per wave, no barrier needed
    const int row = ln >> 2, seg = ln & 3;   // 4 lanes per q-row, 16 cols each
    const unsigned short* srcp = ot + row * 72 + seg * 16;
    unsigned short* dstp = ctx + ((size_t)b * SEQ + qb * 64 + w4 * 16 + row) * HIDDEN
                         + h * 64 + seg * 16;
    *(bf16x8*)(dstp)     = *(const bf16x8*)(srcp);
    *(bf16x8*)(dstp + 8) = *(const bf16x8*)(srcp + 8);
}

// ---------------- output projection: 64x128 tile, 512 blocks = 2/CU ----------------
__global__ __launch_bounds__(256, 2) void outproj(const unsigned short* __restrict__ X,
                                                  const unsigned short* __restrict__ Wt,
                                                  const float* __restrict__ bo,
                                                  float* __restrict__ out) {
    __shared__ __align__(16) unsigned short smem[12288];   // A 4096 | B 8192 elems
    const int mbase = blockIdx.x * 64, nbase = blockIdx.y * 128;
    const int tid = threadIdx.x, w = tid >> 6, ln = tid & 63;
    const int qr = (w >> 1) * 32, qc = (w & 1) * 64;
    const int g = ln >> 4, c16 = ln & 15;

    f32x4 acc[2][4];
    #pragma unroll
    for (int rt = 0; rt < 2; rt++)
        #pragma unroll
        for (int ct = 0; ct < 4; ct++) acc[rt][ct] = (f32x4){0.f, 0.f, 0.f, 0.f};

    for (int kk = 0; kk < HIDDEN; kk += 64) {
        __syncthreads();
        #pragma unroll
        for (int pass = 0; pass < 2; pass++) {      // A: 64 rows
            int L = pass * 256 + tid;
            int r = L >> 3, c = (L & 7) ^ (r & 7);
            gload16(X + (size_t)(mbase + r) * HIDDEN + kk + c * 8,
                    smem + (size_t)(pass * 256 + w * 64) * 8);
        }
        #pragma unroll
        for (int pass = 0; pass < 4; pass++) {      // B: 128 rows
            int L = pass * 256 + tid;
            int r = L >> 3, c = (L & 7) ^ (r & 7);
            gload16(Wt + (size_t)(nbase + r) * HIDDEN + kk + c * 8,
                    smem + 4096 + (size_t)(pass * 256 + w * 64) * 8);
        }
        __syncthreads();
        #pragma unroll
        for (int ks = 0; ks < 2; ks++) {
            bf16x8 af[2], bfr[4];
            #pragma unroll
            for (int rt = 0; rt < 2; rt++) {
                int r = qr + rt * 16 + c16;
                int ch = (g + ks * 4) ^ (r & 7);
                af[rt] = *(const bf16x8*)(smem + (size_t)(r * 8 + ch) * 8);
            }
            #pragma unroll
            for (int ct = 0; ct < 4; ct++) {
                int n = qc + ct * 16 + c16;
                int ch = (g + ks * 4) ^ (n & 7);
                bfr[ct] = *(const bf16x8*)(smem + 4096 + (size_t)(n * 8 + ch) * 8);
            }
            #pragma unroll
            for (int rt = 0; rt < 2; rt++)
                #pragma unroll
                for (int ct = 0; ct < 4; ct++)
                    acc[rt][ct] = __builtin_amdgcn_mfma_f32_16x16x32_bf16(af[rt], bfr[ct], acc[rt][ct], 0, 0, 0);
        }
    }

    float bo_v[4];
    #pragma unroll
    for (int ct = 0; ct < 4; ct++) bo_v[ct] = bo[nbase + qc + ct * 16 + c16];
    #pragma unroll
    for (int rt = 0; rt < 2; rt++)
        #pragma unroll
        for (int ct = 0; ct < 4; ct++)
            #pragma unroll
            for (int r4 = 0; r4 < 4; r4++)
                out[(size_t)(mbase + qr + rt * 16 + g * 4 + r4) * HIDDEN + nbase + qc + ct * 16 + c16]
                    = acc[rt][ct][r4] + bo_v[ct];
}

// ---------------- launch ----------------
extern "C" void kernel_launch(void* const* d_in, const int* in_sizes, int n_in,
                              void* d_out, int out_size, void* d_ws, size_t ws_size,
                              hipStream_t stream) {
    const float* q    = (const float*)d_in[0];
    const float* k    = (const float*)d_in[1];
    const float* v    = (const float*)d_in[2];
    const float* bias = (const float*)d_in[3];
    const float* mask = (const float*)d_in[4];
    const float* Wq   = (const float*)d_in[5];
    const float* bq   = (const float*)d_in[6];
    const float* Wk   = (const float*)d_in[7];
    const float* bk   = (const float*)d_in[8];
    const float* Wv   = (const float*)d_in[9];
    const float* bv   = (const float*)d_in[10];
    const float* Wo   = (const float*)d_in[11];
    const float* bo   = (const float*)d_in[12];

    char* ws = (char*)d_ws;
    unsigned short* biasf  = (unsigned short*)ws;                // 16 MB bf16 frag-tiled
    unsigned short* wt     = (unsigned short*)(ws + 16777216);   // 8 MB
    unsigned short* qh     = (unsigned short*)(ws + 25165824);   // 8 MB
    unsigned short* khs    = (unsigned short*)(ws + 33554432);   // 8 MB frag-packed
    unsigned short* vts    = (unsigned short*)(ws + 41943040);   // 8 MB frag-packed
    unsigned short* ctx    = (unsigned short*)(ws + 50331648);   // 8 MB
    // total ws use: 58,720,256 bytes

    prep<<<2048, 256, 0, stream>>>(Wq, Wk, Wv, Wo, wt, bias, mask, biasf);
    proj_gemm<<<dim3(32, 8, 3), 256, 0, stream>>>(q, k, v, wt, bq, bk, bv, qh, khs, vts);
    attn<<<512, 512, 0, stream>>>(qh, khs, vts, biasf, ctx);
    outproj<<<dim3(64, 8), 256, 0, stream>>>(ctx, wt + (size_t)3 * HIDDEN * HIDDEN, bo,
                                             (float*)d_out);
}

// Round 11
// 267.508 us; speedup vs baseline: 1.0331x; 1.0331x over previous
//
#include <hip/hip_runtime.h>
#include <hip/hip_bf16.h>

#define HIDDEN 1024
#define NHEADS 16
#define DKH   64
#define BATCH 2
#define SEQ   2048
#define MTOT  (BATCH*SEQ)   // 4096

using bf16x8 = __attribute__((ext_vector_type(8))) short;
using f32x4  = __attribute__((ext_vector_type(4))) float;
using u16x4  = __attribute__((ext_vector_type(4))) unsigned short;

__device__ __forceinline__ unsigned short f2bf(float f) {
    union { __hip_bfloat16 h; unsigned short u; } v;
    v.h = __float2bfloat16(f);
    return v.u;
}

__device__ __forceinline__ float asfloat(unsigned int u) {
    union { unsigned int u; float f; } v; v.u = u; return v.f;
}

__device__ __forceinline__ float fexp2(float x) {
#if __has_builtin(__builtin_amdgcn_exp2f)
    return __builtin_amdgcn_exp2f(x);
#else
    return exp2f(x);
#endif
}

// async global->LDS, 16B per lane. LDS ptr must be wave-uniform (HW adds lane*16).
__device__ __forceinline__ void gload16(const unsigned short* g, unsigned short* l) {
    __builtin_amdgcn_global_load_lds((const __attribute__((address_space(1))) void*)g,
                                     (__attribute__((address_space(3))) void*)l, 16, 0, 0);
}

#define L2E 1.44269504088896340736f

// ---------------- prep: W -> Wt bf16 transpose only ----------------
// (bias-prep moved into the proj_gemm launch: it has no dependence on proj's
//  GEMM work, and its HBM streaming hides under proj's latency-bound blocks.)
__global__ __launch_bounds__(256) void prep(const float* __restrict__ Wq,
                                            const float* __restrict__ Wk,
                                            const float* __restrict__ Wv,
                                            const float* __restrict__ Wo,
                                            unsigned short* __restrict__ wt) {
    __shared__ float tile[64][65];
    int r = blockIdx.x;
    const int t = threadIdx.x;
    const int z = r >> 8; r &= 255;
    const int kb = (r >> 4) * 64, nb = (r & 15) * 64;
    const float* W = (z == 0) ? Wq : (z == 1) ? Wk : (z == 2) ? Wv : Wo;
    unsigned short* out = wt + (size_t)z * HIDDEN * HIDDEN;
    #pragma unroll
    for (int i = 0; i < 16; i++) {
        int idx = i * 256 + t; int rr = idx >> 6, c = idx & 63;
        tile[rr][c] = W[(size_t)(kb + rr) * HIDDEN + nb + c];
    }
    __syncthreads();
    #pragma unroll
    for (int i = 0; i < 16; i++) {
        int idx = i * 256 + t; int n = idx >> 6, kk = idx & 63;
        out[(size_t)(nb + n) * HIDDEN + kb + kk] = f2bf(tile[kk][n]);
    }
}

// ---------------- projections (z 0-2) + fused bias-prep (z 3-6) ----------------
// GEMM path: PROVEN r7 config (52.5us): 128x128, A-operand f32 software-pipelined
// (loads for kk+64 issued right after the staging barrier of kk), B via
// global_load_lds with source-swizzle. LDS: A elem (r, slot s) = X[r][s^(r&7)].
// Bias path (z>=3, 1024 blocks): bias+mask -> biasf bf16 fragment-tiled, code
// verbatim from the proven prep version. biasf bf16: [b][qg128][t64][lane64*8],
// lane ln holds q = qg*16 + (ln&15), kv = t*32 + (ln>>4)*8 + i, value *log2e.
// Co-scheduling rationale: bias blocks are HBM-streaming (~132MB), GEMM blocks
// are latency-bound at 15% HBM - complementary pipes on the same CUs.
// q -> qh [bh][q][64] (scaled 0.125*log2e)
// k -> khs [bh][t64][ks2][kvs2][lane64*8]: lane ln holds
//          K[kv = t*32 + (c16>>2)*8 + kvs*4 + (c16&3)][d = ks*32 + quad*8 + i]
// v -> vts [bh][t64][dt4][lane64*8]: lane ln holds V[kv = t*32 + quad*8 + i][d = dt*16 + c16]
__global__ __launch_bounds__(256, 2) void proj_gemm(const float* __restrict__ qf32,
                                                    const float* __restrict__ kf32,
                                                    const float* __restrict__ vf32,
                                                    const unsigned short* __restrict__ Wtall,
                                                    const float* __restrict__ bq,
                                                    const float* __restrict__ bk,
                                                    const float* __restrict__ bv,
                                                    unsigned short* __restrict__ qh,
                                                    unsigned short* __restrict__ khs,
                                                    unsigned short* __restrict__ vts,
                                                    const float* __restrict__ bias,
                                                    const float* __restrict__ mask,
                                                    unsigned short* __restrict__ biasf) {
    __shared__ __align__(16) unsigned short smem[18432];
    const int z = blockIdx.z;
    const int tid = threadIdx.x;

    if (z >= 3) {
        // ---- fused bias-prep block ----
        const int cb = (z - 3) * 256 + blockIdx.y * 32 + blockIdx.x;   // 0..1023
        const int chunk = cb & 3, g2 = (cb >> 2) & 127, b2 = cb >> 9;
        unsigned short (*lb)[520] = (unsigned short (*)[520])smem;     // 16640B < 36864B
        const float* bp = bias + ((size_t)b2 * SEQ + g2 * 16) * SEQ + chunk * 512;
        const float* mp = mask + ((size_t)b2 * SEQ + g2 * 16) * SEQ + chunk * 512;
        // load 16 rows x 512 cols, coalesced along kv
        #pragma unroll
        for (int i = 0; i < 8; i++) {
            int idx = i * 256 + tid;
            int row = idx >> 7, c4 = (idx & 127) * 4;
            float4 bv4 = *(const float4*)(bp + (size_t)row * SEQ + c4);
            float4 mv4 = *(const float4*)(mp + (size_t)row * SEQ + c4);
            union { u16x4 v; unsigned short s[4]; } o;
            o.s[0] = f2bf((bv4.x + mv4.x) * L2E);
            o.s[1] = f2bf((bv4.y + mv4.y) * L2E);
            o.s[2] = f2bf((bv4.z + mv4.z) * L2E);
            o.s[3] = f2bf((bv4.w + mv4.w) * L2E);
            *(u16x4*)&lb[row][c4] = o.v;
        }
        __syncthreads();
        // emit fragment tiles: tt = chunk*16 + ttl
        const int w2 = tid >> 6, ln2 = tid & 63;
        const int quad2 = ln2 >> 4, c162 = ln2 & 15;
        unsigned short* ob = biasf + (((size_t)b2 * 128 + g2) * 64 + chunk * 16) * 512 + ln2 * 8;
        #pragma unroll
        for (int it = 0; it < 4; it++) {
            int ttl = it * 4 + w2;
            *(bf16x8*)(ob + (size_t)ttl * 512) = *(const bf16x8*)&lb[c162][ttl * 32 + quad2 * 8];
        }
        return;
    }

    // ---- GEMM block (verbatim r7 structure) ----
    const float* X  = (z == 0) ? qf32 : (z == 1) ? kf32 : vf32;
    const unsigned short* Wt = Wtall + (size_t)z * HIDDEN * HIDDEN;
    const float* bvec = (z == 0) ? bq : (z == 1) ? bk : bv;
    const int mbase = blockIdx.x * 128, nbase = blockIdx.y * 128;
    const int w = tid >> 6, ln = tid & 63;
    const int qr = (w >> 1) * 64, qc = (w & 1) * 64;
    const int g = ln >> 4, c16 = ln & 15;

    f32x4 acc[4][4];
    #pragma unroll
    for (int rt = 0; rt < 4; rt++)
        #pragma unroll
        for (int ct = 0; ct < 4; ct++) acc[rt][ct] = (f32x4){0.f, 0.f, 0.f, 0.f};

    float4 fa[4][2];
    // prologue: preload k-step 0
    #pragma unroll
    for (int pass = 0; pass < 4; pass++) {
        int L = pass * 256 + tid;
        int r = L >> 3, cc = L & 7;
        const float* p = X + (size_t)(mbase + r) * HIDDEN + cc * 8;
        fa[pass][0] = *(const float4*)p;
        fa[pass][1] = *(const float4*)(p + 4);
    }

    for (int kk = 0; kk < HIDDEN; kk += 64) {
        __syncthreads();
        // B via async DMA first (flies during the A convert)
        #pragma unroll
        for (int pass = 0; pass < 4; pass++) {
            int L = pass * 256 + tid;
            int r = L >> 3, c = (L & 7) ^ (r & 7);
            gload16(Wt + (size_t)(nbase + r) * HIDDEN + kk + c * 8,
                    smem + 8192 + (size_t)(pass * 256 + w * 64) * 8);
        }
        // A: convert prefetched regs, swizzled ds_write
        #pragma unroll
        for (int pass = 0; pass < 4; pass++) {
            int L = pass * 256 + tid;
            int r = L >> 3, cc = L & 7;
            int cs = cc ^ (r & 7);
            union { bf16x8 v; unsigned short s[8]; } o;
            o.s[0] = f2bf(fa[pass][0].x); o.s[1] = f2bf(fa[pass][0].y);
            o.s[2] = f2bf(fa[pass][0].z); o.s[3] = f2bf(fa[pass][0].w);
            o.s[4] = f2bf(fa[pass][1].x); o.s[5] = f2bf(fa[pass][1].y);
            o.s[6] = f2bf(fa[pass][1].z); o.s[7] = f2bf(fa[pass][1].w);
            *(bf16x8*)(smem + (size_t)(r * 8 + cs) * 8) = o.v;
        }
        __syncthreads();
        // issue next k-step's A loads NOW; they complete during the MFMA phase
        if (kk + 64 < HIDDEN) {
            #pragma unroll
            for (int pass = 0; pass < 4; pass++) {
                int L = pass * 256 + tid;
                int r = L >> 3, cc = L & 7;
                const float* p = X + (size_t)(mbase + r) * HIDDEN + (kk + 64) + cc * 8;
                fa[pass][0] = *(const float4*)p;
                fa[pass][1] = *(const float4*)(p + 4);
            }
        }
        #pragma unroll
        for (int ks = 0; ks < 2; ks++) {
            bf16x8 af[4], bfr[4];
            #pragma unroll
            for (int rt = 0; rt < 4; rt++) {
                int r = qr + rt * 16 + c16;
                int ch = (g + ks * 4) ^ (r & 7);
                af[rt] = *(const bf16x8*)(smem + (size_t)(r * 8 + ch) * 8);
            }
            #pragma unroll
            for (int ct = 0; ct < 4; ct++) {
                int n = qc + ct * 16 + c16;
                int ch = (g + ks * 4) ^ (n & 7);
                bfr[ct] = *(const bf16x8*)(smem + 8192 + (size_t)(n * 8 + ch) * 8);
            }
            #pragma unroll
            for (int rt = 0; rt < 4; rt++)
                #pragma unroll
                for (int ct = 0; ct < 4; ct++)
                    acc[rt][ct] = __builtin_amdgcn_mfma_f32_16x16x32_bf16(af[rt], bfr[ct], acc[rt][ct], 0, 0, 0);
        }
    }
    __syncthreads();

    const float scale = (z == 0) ? (0.125f * L2E) : 1.0f;
    float bias_v[4];
    #pragma unroll
    for (int ct = 0; ct < 4; ct++) bias_v[ct] = bvec[nbase + qc + ct * 16 + c16];

    unsigned short* eld = smem + w * 4608;   // 64x72 per wave
    #pragma unroll
    for (int rt = 0; rt < 4; rt++)
        #pragma unroll
        for (int ct = 0; ct < 4; ct++)
            #pragma unroll
            for (int r4 = 0; r4 < 4; r4++) {
                int row_l = rt * 16 + g * 4 + r4;    // pos (local)
                int col_l = ct * 16 + c16;           // n (local)
                float val = (acc[rt][ct][r4] + bias_v[ct]) * scale;
                if (z == 2) eld[col_l * 72 + row_l] = f2bf(val);  // [d][pos]
                else        eld[row_l * 72 + col_l] = f2bf(val);  // [pos][d]
            }
    __syncthreads();

    const int b = mbase >> 11;
    const int pos0 = (mbase & 2047) + qr;   // multiple of 64
    const int h = (nbase + qc) >> 6;
    const int bh = b * NHEADS + h;
    if (z == 0) {
        const int row8 = ln >> 3, col8 = (ln & 7) * 8;
        unsigned short* dst0 = qh + ((size_t)bh * SEQ + pos0) * DKH;
        #pragma unroll
        for (int j = 0; j < 8; j++) {
            int row = j * 8 + row8;
            *(bf16x8*)(dst0 + row * 64 + col8) = *(const bf16x8*)&eld[row * 72 + col8];
        }
    } else if (z == 1) {
        unsigned short* base = khs + ((size_t)bh * 64 + (pos0 >> 5)) * 2048;
        const int kvp = (c16 >> 2) * 8 + (c16 & 3);
        #pragma unroll
        for (int j = 0; j < 8; j++) {
            int tloc = j >> 2, ks = (j >> 1) & 1, kvs = j & 1;
            int kvl = tloc * 32 + kvp + kvs * 4;
            *(bf16x8*)(base + tloc * 2048 + ks * 1024 + kvs * 512 + ln * 8)
                = *(const bf16x8*)&eld[kvl * 72 + ks * 32 + g * 8];
        }
    } else {
        unsigned short* base = vts + ((size_t)bh * 64 + (pos0 >> 5)) * 2048;
        #pragma unroll
        for (int j = 0; j < 8; j++) {
            int tloc = j >> 2, dt = j & 3;
            *(bf16x8*)(base + tloc * 2048 + dt * 512 + ln * 8)
                = *(const bf16x8*)&eld[(dt * 16 + c16) * 72 + tloc * 32 + g * 8];
        }
    }
}

// ---------------- attention ----------------
// PROVEN r7-input config (<=52.3us): block = 64 q x 2048 kv, 4 waves x 16 q,
// 1024 blocks = 4/CU. (r10's 2-head 512-thread variant regressed to 56us:
// FETCH dropped as predicted but the 8-wave barrier coupling cost more.)
// bf16 bias fragments with 1-tile prefetch slack (mov-free via 2x-unrolled T);
// ones-MFMA softmax denominator; unnormalized exp2 softmax.
__global__ __launch_bounds__(256, 4) void attn(const unsigned short* __restrict__ qh,
                                               const unsigned short* __restrict__ khs,
                                               const unsigned short* __restrict__ vts,
                                               const unsigned short* __restrict__ biasf,
                                               unsigned short* __restrict__ ctx) {
    __shared__ __align__(16) unsigned short smem[16384];   // K 8192 | V 8192 elems
    const int tid = threadIdx.x, w = tid >> 6, ln = tid & 63;
    const int quad = ln >> 4, c16 = ln & 15;
    // XCD swizzle: 4 bh per XCD, all 32 q-blocks of a bh on one XCD (K/V L2 reuse)
    const int bid = blockIdx.x;
    const int xcd = bid & 7, jj = bid >> 3;    // jj 0..127
    const int bh = xcd * 4 + (jj >> 5);
    const int qb = jj & 31;                    // 64-row q block
    const int b = bh >> 4, h = bh & 15;

    // Q B-fragments (persistent); wave owns 16 q rows
    bf16x8 qf[2];
    {
        const unsigned short* qp = qh + ((size_t)bh * SEQ + qb * 64 + w * 16 + c16) * DKH + quad * 8;
        qf[0] = *(const bf16x8*)qp;
        qf[1] = *(const bf16x8*)(qp + 32);
    }

    const unsigned short* kT = khs + (size_t)bh * 131072;
    const unsigned short* vT = vts + (size_t)bh * 131072;
    // wave's 16 q rows correspond to bias group g = qb*4 + w (bf16 fragments)
    const unsigned short* bb = biasf + (((size_t)(b * 128 + qb * 4 + w) * 64) * 512) + ln * 8;

    // ones A-fragment for the denominator MFMA
    const short one_bf = (short)0x3F80;
    bf16x8 vones = {one_bf, one_bf, one_bf, one_bf, one_bf, one_bf, one_bf, one_bf};

    f32x4 accv[4];
    #pragma unroll
    for (int dt = 0; dt < 4; dt++) accv[dt] = (f32x4){0.f, 0.f, 0.f, 0.f};
    f32x4 dsum = (f32x4){0.f, 0.f, 0.f, 0.f};

    bf16x8 bA[4], bB[4];
    #pragma unroll
    for (int j = 0; j < 4; j++) bA[j] = *(const bf16x8*)(bb + j * 512);   // tile 0

    // one half-tile: stage K/V for T, prefetch bias for T+1 into bn (1-tile
    // slack: drained by T+1's barrier), compute tile T consuming bc.
    #define HALF_TILE(T, bc, bn)                                                        \
    {                                                                                   \
        __syncthreads();   /* previous tile's ds_reads done */                          \
        {                                                                               \
            const unsigned short* ksrc = kT + (T) * 8192 + w * 512 + ln * 8;            \
            const unsigned short* vsrc = vT + (T) * 8192 + w * 512 + ln * 8;            \
            unsigned short* lk = smem + w * 512;                                        \
            unsigned short* lv = smem + 8192 + w * 512;                                 \
            _Pragma("unroll")                                                           \
            for (int p = 0; p < 4; p++) {                                               \
                gload16(ksrc + p * 2048, lk + p * 2048);                                \
                gload16(vsrc + p * 2048, lv + p * 2048);                                \
            }                                                                           \
        }                                                                               \
        {                                                                               \
            const int Tn = ((T) < 15) ? (T) + 1 : 15;                                   \
            _Pragma("unroll")                                                           \
            for (int j = 0; j < 4; j++)                                                 \
                bn[j] = *(const bf16x8*)(bb + (size_t)(Tn * 4 + j) * 512);              \
        }                                                                               \
        __syncthreads();   /* drain global_load_lds */                                  \
        _Pragma("unroll")                                                               \
        for (int j = 0; j < 4; j++) {                                                   \
            bf16x8 kf00 = *(const bf16x8*)(smem + j * 2048 + ln * 8);                   \
            bf16x8 kf01 = *(const bf16x8*)(smem + j * 2048 + 512 + ln * 8);             \
            bf16x8 kf10 = *(const bf16x8*)(smem + j * 2048 + 1024 + ln * 8);            \
            bf16x8 kf11 = *(const bf16x8*)(smem + j * 2048 + 1536 + ln * 8);            \
            bf16x8 vf[4];                                                               \
            _Pragma("unroll")                                                           \
            for (int dt = 0; dt < 4; dt++)                                              \
                vf[dt] = *(const bf16x8*)(smem + 8192 + j * 2048 + dt * 512 + ln * 8);  \
            const unsigned int* bd = (const unsigned int*)&bc[j];                       \
            f32x4 s0, s1;                                                               \
            s0[0] = asfloat(bd[0] << 16); s0[1] = asfloat(bd[0] & 0xFFFF0000u);         \
            s0[2] = asfloat(bd[1] << 16); s0[3] = asfloat(bd[1] & 0xFFFF0000u);         \
            s1[0] = asfloat(bd[2] << 16); s1[1] = asfloat(bd[2] & 0xFFFF0000u);         \
            s1[2] = asfloat(bd[3] << 16); s1[3] = asfloat(bd[3] & 0xFFFF0000u);         \
            s0 = __builtin_amdgcn_mfma_f32_16x16x32_bf16(kf00, qf[0], s0, 0, 0, 0);     \
            s0 = __builtin_amdgcn_mfma_f32_16x16x32_bf16(kf10, qf[1], s0, 0, 0, 0);     \
            s1 = __builtin_amdgcn_mfma_f32_16x16x32_bf16(kf01, qf[0], s1, 0, 0, 0);     \
            s1 = __builtin_amdgcn_mfma_f32_16x16x32_bf16(kf11, qf[1], s1, 0, 0, 0);     \
            _Pragma("unroll")                                                           \
            for (int r = 0; r < 4; r++) { s0[r] = fexp2(s0[r]); s1[r] = fexp2(s1[r]); } \
            union { bf16x8 v; __hip_bfloat162 hh[4]; } pu;                              \
            pu.hh[0] = __float22bfloat162_rn(make_float2(s0[0], s0[1]));                \
            pu.hh[1] = __float22bfloat162_rn(make_float2(s0[2], s0[3]));                \
            pu.hh[2] = __float22bfloat162_rn(make_float2(s1[0], s1[1]));                \
            pu.hh[3] = __float22bfloat162_rn(make_float2(s1[2], s1[3]));                \
            dsum = __builtin_amdgcn_mfma_f32_16x16x32_bf16(vones, pu.v, dsum, 0, 0, 0); \
            _Pragma("unroll")                                                           \
            for (int dt = 0; dt < 4; dt++)                                              \
                accv[dt] = __builtin_amdgcn_mfma_f32_16x16x32_bf16(vf[dt], pu.v,        \
                                                                   accv[dt], 0, 0, 0); \
        }                                                                               \
    }

    for (int T = 0; T < 16; T += 2) {
        HALF_TILE(T,     bA, bB)
        HALF_TILE(T + 1, bB, bA)
    }
    #undef HALF_TILE

    // epilogue: normalize (dsum rows all equal; lane's col c16 = its q row),
    // per-wave LDS transpose (reuse smem), coalesced store
    const float inv = 1.0f / dsum[0];
    __syncthreads();   // all waves done reading staged K/V
    unsigned short* ot = smem + w * 1152;   // 16 x 72 per wave
    #pragma unroll
    for (int dt = 0; dt < 4; dt++)
        #pragma unroll
        for (int r = 0; r < 4; r += 2) {
            union { __hip_bfloat162 hh; unsigned int u; } pk;
            pk.hh = __float22bfloat162_rn(make_float2(accv[dt][r] * inv,
                                                     accv[dt][r + 1] * inv));
            *(unsigned int*)&ot[c16 * 72 + dt * 16 + quad * 4 + r] = pk.u;
        }
    // wave-local write->read: in-order per wave, no barrier needed
    const int row = ln >> 2, seg = ln & 3;   // 4 lanes per q-row, 16 cols each
    const unsigned short* srcp = ot + row * 72 + seg * 16;
    unsigned short* dstp = ctx + ((size_t)b * SEQ + qb * 64 + w * 16 + row) * HIDDEN
                         + h * 64 + seg * 16;
    *(bf16x8*)(dstp)     = *(const bf16x8*)(srcp);
    *(bf16x8*)(dstp + 8) = *(const bf16x8*)(srcp + 8);
}

// ---------------- output projection: 64x128 tile, 512 blocks = 2/CU ----------------
__global__ __launch_bounds__(256, 2) void outproj(const unsigned short* __restrict__ X,
                                                  const unsigned short* __restrict__ Wt,
                                                  const float* __restrict__ bo,
                                                  float* __restrict__ out) {
    __shared__ __align__(16) unsigned short smem[12288];   // A 4096 | B 8192 elems
    const int mbase = blockIdx.x * 64, nbase = blockIdx.y * 128;
    const int tid = threadIdx.x, w = tid >> 6, ln = tid & 63;
    const int qr = (w >> 1) * 32, qc = (w & 1) * 64;
    const int g = ln >> 4, c16 = ln & 15;

    f32x4 acc[2][4];
    #pragma unroll
    for (int rt = 0; rt < 2; rt++)
        #pragma unroll
        for (int ct = 0; ct < 4; ct++) acc[rt][ct] = (f32x4){0.f, 0.f, 0.f, 0.f};

    for (int kk = 0; kk < HIDDEN; kk += 64) {
        __syncthreads();
        #pragma unroll
        for (int pass = 0; pass < 2; pass++) {      // A: 64 rows
            int L = pass * 256 + tid;
            int r = L >> 3, c = (L & 7) ^ (r & 7);
            gload16(X + (size_t)(mbase + r) * HIDDEN + kk + c * 8,
                    smem + (size_t)(pass * 256 + w * 64) * 8);
        }
        #pragma unroll
        for (int pass = 0; pass < 4; pass++) {      // B: 128 rows
            int L = pass * 256 + tid;
            int r = L >> 3, c = (L & 7) ^ (r & 7);
            gload16(Wt + (size_t)(nbase + r) * HIDDEN + kk + c * 8,
                    smem + 4096 + (size_t)(pass * 256 + w * 64) * 8);
        }
        __syncthreads();
        #pragma unroll
        for (int ks = 0; ks < 2; ks++) {
            bf16x8 af[2], bfr[4];
            #pragma unroll
            for (int rt = 0; rt < 2; rt++) {
                int r = qr + rt * 16 + c16;
                int ch = (g + ks * 4) ^ (r & 7);
                af[rt] = *(const bf16x8*)(smem + (size_t)(r * 8 + ch) * 8);
            }
            #pragma unroll
            for (int ct = 0; ct < 4; ct++) {
                int n = qc + ct * 16 + c16;
                int ch = (g + ks * 4) ^ (n & 7);
                bfr[ct] = *(const bf16x8*)(smem + 4096 + (size_t)(n * 8 + ch) * 8);
            }
            #pragma unroll
            for (int rt = 0; rt < 2; rt++)
                #pragma unroll
                for (int ct = 0; ct < 4; ct++)
                    acc[rt][ct] = __builtin_amdgcn_mfma_f32_16x16x32_bf16(af[rt], bfr[ct], acc[rt][ct], 0, 0, 0);
        }
    }

    float bo_v[4];
    #pragma unroll
    for (int ct = 0; ct < 4; ct++) bo_v[ct] = bo[nbase + qc + ct * 16 + c16];
    #pragma unroll
    for (int rt = 0; rt < 2; rt++)
        #pragma unroll
        for (int ct = 0; ct < 4; ct++)
            #pragma unroll
            for (int r4 = 0; r4 < 4; r4++)
                out[(size_t)(mbase + qr + rt * 16 + g * 4 + r4) * HIDDEN + nbase + qc + ct * 16 + c16]
                    = acc[rt][ct][r4] + bo_v[ct];
}

// ---------------- launch ----------------
extern "C" void kernel_launch(void* const* d_in, const int* in_sizes, int n_in,
                              void* d_out, int out_size, void* d_ws, size_t ws_size,
                              hipStream_t stream) {
    const float* q    = (const float*)d_in[0];
    const float* k    = (const float*)d_in[1];
    const float* v    = (const float*)d_in[2];
    const float* bias = (const float*)d_in[3];
    const float* mask = (const float*)d_in[4];
    const float* Wq   = (const float*)d_in[5];
    const float* bq   = (const float*)d_in[6];
    const float* Wk   = (const float*)d_in[7];
    const float* bk   = (const float*)d_in[8];
    const float* Wv   = (const float*)d_in[9];
    const float* bv   = (const float*)d_in[10];
    const float* Wo   = (const float*)d_in[11];
    const float* bo   = (const float*)d_in[12];

    char* ws = (char*)d_ws;
    unsigned short* biasf  = (unsigned short*)ws;                // 16 MB bf16 frag-tiled
    unsigned short* wt     = (unsigned short*)(ws + 16777216);   // 8 MB
    unsigned short* qh     = (unsigned short*)(ws + 25165824);   // 8 MB
    unsigned short* khs    = (unsigned short*)(ws + 33554432);   // 8 MB frag-packed
    unsigned short* vts    = (unsigned short*)(ws + 41943040);   // 8 MB frag-packed
    unsigned short* ctx    = (unsigned short*)(ws + 50331648);   // 8 MB
    // total ws use: 58,720,256 bytes

    prep<<<1024, 256, 0, stream>>>(Wq, Wk, Wv, Wo, wt);
    proj_gemm<<<dim3(32, 8, 7), 256, 0, stream>>>(q, k, v, wt, bq, bk, bv,
                                                  qh, khs, vts, bias, mask, biasf);
    attn<<<1024, 256, 0, stream>>>(qh, khs, vts, biasf, ctx);
    outproj<<<dim3(64, 8), 256, 0, stream>>>(ctx, wt + (size_t)3 * HIDDEN * HIDDEN, bo,
                                             (float*)d_out);
}